// Round 10
// baseline (225.114 us; speedup 1.0000x reference)
//
#include <hip/hip_runtime.h>

#define NB 128
#define NS 100
#define NPRED 24
#define NHID 256
#define NSTEPS 16
#define NCTX 96
// 400 blocks x 256 thr (4 waves). Block = TWO groups of 16 rows (A,B).
// Wave w owns hidden channels [64w,64w+64); W2/W1/W3 slices in registers,
// shared across both groups. Layer 3 split by k-chunk + LDS all-reduce.
// 2 barriers per step serve both groups. LDS 48 KB; 2 blocks/CU.

typedef float f32x4 __attribute__((ext_vector_type(4)));
typedef short bf16x8 __attribute__((ext_vector_type(8)));

__device__ __forceinline__ unsigned short f2bf(float f) {
    union { float f; unsigned u; } v; v.f = f;
    return (unsigned short)((v.u + 0x7fffu + ((v.u >> 16) & 1u)) >> 16);
}
__device__ __forceinline__ unsigned pk2(float lo, float hi) {
    return (unsigned)f2bf(lo) | ((unsigned)f2bf(hi) << 16);
}
// 1-op RNE bf16 pack (same rounding as f2bf)
__device__ __forceinline__ unsigned cvtpk(float lo, float hi) {
    unsigned r;
    asm("v_cvt_pk_bf16_f32 %0, %1, %2" : "=v"(r) : "v"(lo), "v"(hi));
    return r;
}
__device__ __forceinline__ bf16x8 mk8(unsigned a, unsigned b, unsigned c, unsigned d) {
    union { unsigned u[4]; bf16x8 v; } x;
    x.u[0] = a; x.u[1] = b; x.u[2] = c; x.u[3] = d;
    return x.v;
}
__device__ __forceinline__ f32x4 bf4_to_f32x4(const unsigned short* pA) {
    uint2 uu = *(const uint2*)pA;
    union { unsigned u; float f; } c0, c1, c2, c3;
    c0.u = uu.x << 16; c1.u = uu.x & 0xffff0000u;
    c2.u = uu.y << 16; c3.u = uu.y & 0xffff0000u;
    f32x4 r; r.x = c0.f; r.y = c1.f; r.z = c2.f; r.w = c3.f;
    return r;
}
__device__ __forceinline__ f32x4 up4(unsigned a, unsigned b) {
    union { unsigned u; float f; } c0, c1, c2, c3;
    c0.u = a << 16; c1.u = a & 0xffff0000u;
    c2.u = b << 16; c3.u = b & 0xffff0000u;
    f32x4 r; r.x = c0.f; r.y = c1.f; r.z = c2.f; r.w = c3.f;
    return r;
}
__device__ __forceinline__ f32x4 relu4(f32x4 a) {
    a.x = fmaxf(a.x, 0.f); a.y = fmaxf(a.y, 0.f);
    a.z = fmaxf(a.z, 0.f); a.w = fmaxf(a.w, 0.f);
    return a;
}

// k-slot permutation within a 32-wide k-block at (lane l, elem e):
//   k_local = 16*(e>>2) + 4*(l>>4) + (e&3)
// Applied identically to A and B fragments (numerically verified R2-R9).

// prep -> d_ws (ushorts): W1F [0,8192) | W3F [8192,16384) | W2F [16384,81920)
__global__ void prep_kernel(const float* __restrict__ W1,
                            const float* __restrict__ W2,
                            const float* __restrict__ W3,
                            unsigned short* __restrict__ wsf) {
    int i = blockIdx.x * 256 + threadIdx.x;   // 0..81919
    if (i < 8192) {
        int T = i >> 9, ll = (i >> 3) & 63, e = i & 7;
        int k = 16 * (e >> 2) + 4 * (ll >> 4) + (e & 3);
        int m = 16 * T + (ll & 15);
        wsf[i] = (k <= 24) ? f2bf(W1[k * NHID + m]) : (unsigned short)0;
    } else if (i < 16384) {
        int idx = i - 8192;
        int ks = idx >> 10, T = (idx >> 9) & 1, ll = (idx >> 3) & 63, e = idx & 7;
        int k = 32 * ks + 16 * (e >> 2) + 4 * (ll >> 4) + (e & 3);
        int m = 16 * T + (ll & 15);
        wsf[i] = (m < NPRED) ? f2bf(W3[k * NPRED + m]) : (unsigned short)0;
    } else {
        int idx = i - 16384;
        int ks = idx >> 13, T = (idx >> 9) & 15, ll = (idx >> 3) & 63, e = idx & 7;
        int k = 32 * ks + 16 * (e >> 2) + 4 * (ll >> 4) + (e & 3);
        int m = 16 * T + (ll & 15);
        wsf[i] = f2bf(W2[k * NHID + m]);
    }
}

__global__ __launch_bounds__(256, 2) void fm_kernel(
    const float* __restrict__ past_target,
    const float* __restrict__ z0g,
    const float* __restrict__ W1, const float* __restrict__ b1,
    const float* __restrict__ b2, const float* __restrict__ b3,
    const unsigned short* __restrict__ wsf,
    float* __restrict__ out) {
    __shared__ __attribute__((aligned(16))) unsigned short cbF[8192]; // 16 KB (2 grp)
    __shared__ __attribute__((aligned(16))) unsigned exA[4096];       // 16 KB h1 x2
    __shared__ __attribute__((aligned(16))) float vred[4096];         // 16 KB v  x2
    __shared__ float locS[32];

    const int tid = threadIdx.x;
    const int blk = blockIdx.x;      // 0..399; rows [blk*32, blk*32+32)

    // ---- one-time: fp32 cbias -> bf16 C-frags for 32 rows ----
    {
        const int r = tid >> 3;          // row-in-block 0..31
        const int cc = tid & 7;          // 32-ch chunk
        const int Rr = blk * 32 + r;
        const int bb = Rr & 127;
        const float* ctxp = past_target + bb * NCTX;
        float asum = 0.f;
        for (int k = 0; k < NCTX; k++) asum += fabsf(ctxp[k]);
        float loc = fmaxf(asum * (1.f / (float)NCTX), 1e-6f);
        if (cc == 0) locS[r] = loc;
        float inv = 1.f / loc;
        f32x4 acc[8];
        const float* b1p = b1 + 32 * cc;
#pragma unroll
        for (int u = 0; u < 8; u++) acc[u] = *(const f32x4*)(b1p + 4 * u);
        for (int k = 0; k < NCTX; k++) {
            float sx = ctxp[k] * inv;
            const f32x4* wr = (const f32x4*)(W1 + (26 + k) * NHID + 32 * cc);
#pragma unroll
            for (int u = 0; u < 8; u++) {
                f32x4 w = wr[u];
                acc[u].x += sx * w.x; acc[u].y += sx * w.y;
                acc[u].z += sx * w.z; acc[u].w += sx * w.w;
            }
        }
        const int G = r >> 4, rr = r & 15;
#pragma unroll
        for (int u = 0; u < 8; u++) {
            int T = 2 * cc + (u >> 2), qq = u & 3;
            int base = G * 4096 + T * 256 + qq * 64 + rr * 4;
            cbF[base + 0] = f2bf(acc[u].x);
            cbF[base + 1] = f2bf(acc[u].y);
            cbF[base + 2] = f2bf(acc[u].z);
            cbF[base + 3] = f2bf(acc[u].w);
        }
    }

    const int w = tid >> 6;          // wave 0..3: owns hidden ch [64w,64w+64)
    const int l = tid & 63;
    const int q = l >> 4, p = l & 15;
    const int RA = blk * 32 + p, RB = RA + 16;
    const int sA = RA >> 7, bA = RA & 127;
    const int sB = RB >> 7, bB = RB & 127;
    const int l8 = l * 8;

    // ---- persistent registers: weights (shared by both groups) ----
    bf16x8 w1r[4], w2r[32], w3r[4];
#pragma unroll
    for (int j = 0; j < 4; j++)
        w1r[j] = *(const bf16x8*)(wsf + (4 * w + j) * 512 + l8);
#pragma unroll
    for (int ks = 0; ks < 8; ks++)
#pragma unroll
        for (int j = 0; j < 4; j++)
            w2r[ks * 4 + j] = *(const bf16x8*)(wsf + 16384 + (ks * 16 + 4 * w + j) * 512 + l8);
#pragma unroll
    for (int d = 0; d < 2; d++)
#pragma unroll
        for (int tt = 0; tt < 2; tt++)
            w3r[2 * d + tt] = *(const bf16x8*)(wsf + 8192 + (2 * w + d) * 1024 + tt * 512 + l8);

    // biases packed bf16 (saves regs; b2/b3 tiny influence, verified R8)
    unsigned b2p[8];
#pragma unroll
    for (int j = 0; j < 4; j++) {
        int ch = (4 * w + j) * 16 + 4 * q;
        b2p[2 * j]     = pk2(b2[ch], b2[ch + 1]);
        b2p[2 * j + 1] = pk2(b2[ch + 2], b2[ch + 3]);
    }
    unsigned b3p[4];
    b3p[0] = pk2(b3[4 * q], b3[4 * q + 1]);
    b3p[1] = pk2(b3[4 * q + 2], b3[4 * q + 3]);
    b3p[2] = (q < 2) ? pk2(b3[16 + 4 * q], b3[16 + 4 * q + 1]) : 0u;
    b3p[3] = (q < 2) ? pk2(b3[16 + 4 * q + 2], b3[16 + 4 * q + 3]) : 0u;

    // ---- z states (replicated across waves; fixed-order math) ----
    f32x4 zsA0, zsA1, zsB0, zsB1;
    {
        const f32x4* zrA = (const f32x4*)(z0g + RA * NPRED);
        const f32x4* zrB = (const f32x4*)(z0g + RB * NPRED);
        f32x4 zz = {0.f, 0.f, 0.f, 0.f};
        zsA0 = zrA[q]; zsA1 = zz; if (q < 2) zsA1 = zrA[4 + q];
        zsB0 = zrB[q]; zsB1 = zz; if (q < 2) zsB1 = zrB[4 + q];
    }

    __syncthreads();   // cbF + locS ready

    const float dt = 1.f / (float)NSTEPS;
#pragma unroll 1
    for (int step = 0; step < NSTEPS; step++) {
        // launder cbF base so reads can't be hoisted into 32 persistent regs
        const unsigned short* cbq = cbF + q * 64 + p * 4;
        asm volatile("" : "+v"(cbq));

        float t = 1.f - (float)step * dt;
        float zA10 = (q == 2) ? t : zsA1.x;
        float zB10 = (q == 2) ? t : zsB1.x;
        bf16x8 bzA = mk8(cvtpk(zsA0.x, zsA0.y), cvtpk(zsA0.z, zsA0.w),
                         cvtpk(zA10, zsA1.y), cvtpk(zsA1.z, zsA1.w));
        bf16x8 bzB = mk8(cvtpk(zsB0.x, zsB0.y), cvtpk(zsB0.z, zsB0.w),
                         cvtpk(zB10, zsB1.y), cvtpk(zsB1.z, zsB1.w));

        // ---- layer 1, groups A & B: 8 MFMA -> exA[0],exA[1] ----
#pragma unroll
        for (int j = 0; j < 4; j++) {
            f32x4 cA = bf4_to_f32x4(cbq + (4 * w + j) * 256);
            f32x4 hA = relu4(__builtin_amdgcn_mfma_f32_16x16x32_bf16(w1r[j], bzA, cA, 0, 0, 0));
            exA[(8 * w + 2 * j) * 64 + l]     = cvtpk(hA.x, hA.y);
            exA[(8 * w + 2 * j + 1) * 64 + l] = cvtpk(hA.z, hA.w);
            f32x4 cB = bf4_to_f32x4(cbq + 4096 + (4 * w + j) * 256);
            f32x4 hB = relu4(__builtin_amdgcn_mfma_f32_16x16x32_bf16(w1r[j], bzB, cB, 0, 0, 0));
            exA[2048 + (8 * w + 2 * j) * 64 + l]     = cvtpk(hB.x, hB.y);
            exA[2048 + (8 * w + 2 * j + 1) * 64 + l] = cvtpk(hB.z, hB.w);
        }
        __syncthreads();   // bar1: h1 for both groups exchanged

        // ---- layer 2 + layer 3 partial, group A ----
        {
            f32x4 a0 = {0.f, 0.f, 0.f, 0.f}, a1 = a0, a2 = a0, a3 = a0;
#pragma unroll
            for (int ks = 0; ks < 8; ks++) {
                bf16x8 bb = mk8(exA[(4 * ks) * 64 + l], exA[(4 * ks + 1) * 64 + l],
                                exA[(4 * ks + 2) * 64 + l], exA[(4 * ks + 3) * 64 + l]);
                a0 = __builtin_amdgcn_mfma_f32_16x16x32_bf16(w2r[ks * 4 + 0], bb, a0, 0, 0, 0);
                a1 = __builtin_amdgcn_mfma_f32_16x16x32_bf16(w2r[ks * 4 + 1], bb, a1, 0, 0, 0);
                a2 = __builtin_amdgcn_mfma_f32_16x16x32_bf16(w2r[ks * 4 + 2], bb, a2, 0, 0, 0);
                a3 = __builtin_amdgcn_mfma_f32_16x16x32_bf16(w2r[ks * 4 + 3], bb, a3, 0, 0, 0);
            }
            f32x4 h0 = relu4(a0 + up4(b2p[0], b2p[1]));
            f32x4 h1 = relu4(a1 + up4(b2p[2], b2p[3]));
            f32x4 h2 = relu4(a2 + up4(b2p[4], b2p[5]));
            f32x4 h3 = relu4(a3 + up4(b2p[6], b2p[7]));
            bf16x8 bbA = mk8(cvtpk(h0.x, h0.y), cvtpk(h0.z, h0.w),
                             cvtpk(h1.x, h1.y), cvtpk(h1.z, h1.w));
            bf16x8 bbB = mk8(cvtpk(h2.x, h2.y), cvtpk(h2.z, h2.w),
                             cvtpk(h3.x, h3.y), cvtpk(h3.z, h3.w));
            f32x4 v0 = {0.f, 0.f, 0.f, 0.f}, v1 = v0;
            v0 = __builtin_amdgcn_mfma_f32_16x16x32_bf16(w3r[0], bbA, v0, 0, 0, 0);
            v1 = __builtin_amdgcn_mfma_f32_16x16x32_bf16(w3r[1], bbA, v1, 0, 0, 0);
            v0 = __builtin_amdgcn_mfma_f32_16x16x32_bf16(w3r[2], bbB, v0, 0, 0, 0);
            v1 = __builtin_amdgcn_mfma_f32_16x16x32_bf16(w3r[3], bbB, v1, 0, 0, 0);
            vred[(8 * w + 0) * 64 + l] = v0.x; vred[(8 * w + 1) * 64 + l] = v0.y;
            vred[(8 * w + 2) * 64 + l] = v0.z; vred[(8 * w + 3) * 64 + l] = v0.w;
            vred[(8 * w + 4) * 64 + l] = v1.x; vred[(8 * w + 5) * 64 + l] = v1.y;
            vred[(8 * w + 6) * 64 + l] = v1.z; vred[(8 * w + 7) * 64 + l] = v1.w;
        }
        // ---- layer 2 + layer 3 partial, group B ----
        {
            f32x4 a0 = {0.f, 0.f, 0.f, 0.f}, a1 = a0, a2 = a0, a3 = a0;
#pragma unroll
            for (int ks = 0; ks < 8; ks++) {
                bf16x8 bb = mk8(exA[2048 + (4 * ks) * 64 + l], exA[2048 + (4 * ks + 1) * 64 + l],
                                exA[2048 + (4 * ks + 2) * 64 + l], exA[2048 + (4 * ks + 3) * 64 + l]);
                a0 = __builtin_amdgcn_mfma_f32_16x16x32_bf16(w2r[ks * 4 + 0], bb, a0, 0, 0, 0);
                a1 = __builtin_amdgcn_mfma_f32_16x16x32_bf16(w2r[ks * 4 + 1], bb, a1, 0, 0, 0);
                a2 = __builtin_amdgcn_mfma_f32_16x16x32_bf16(w2r[ks * 4 + 2], bb, a2, 0, 0, 0);
                a3 = __builtin_amdgcn_mfma_f32_16x16x32_bf16(w2r[ks * 4 + 3], bb, a3, 0, 0, 0);
            }
            f32x4 h0 = relu4(a0 + up4(b2p[0], b2p[1]));
            f32x4 h1 = relu4(a1 + up4(b2p[2], b2p[3]));
            f32x4 h2 = relu4(a2 + up4(b2p[4], b2p[5]));
            f32x4 h3 = relu4(a3 + up4(b2p[6], b2p[7]));
            bf16x8 bbA = mk8(cvtpk(h0.x, h0.y), cvtpk(h0.z, h0.w),
                             cvtpk(h1.x, h1.y), cvtpk(h1.z, h1.w));
            bf16x8 bbB = mk8(cvtpk(h2.x, h2.y), cvtpk(h2.z, h2.w),
                             cvtpk(h3.x, h3.y), cvtpk(h3.z, h3.w));
            f32x4 v0 = {0.f, 0.f, 0.f, 0.f}, v1 = v0;
            v0 = __builtin_amdgcn_mfma_f32_16x16x32_bf16(w3r[0], bbA, v0, 0, 0, 0);
            v1 = __builtin_amdgcn_mfma_f32_16x16x32_bf16(w3r[1], bbA, v1, 0, 0, 0);
            v0 = __builtin_amdgcn_mfma_f32_16x16x32_bf16(w3r[2], bbB, v0, 0, 0, 0);
            v1 = __builtin_amdgcn_mfma_f32_16x16x32_bf16(w3r[3], bbB, v1, 0, 0, 0);
            vred[2048 + (8 * w + 0) * 64 + l] = v0.x; vred[2048 + (8 * w + 1) * 64 + l] = v0.y;
            vred[2048 + (8 * w + 2) * 64 + l] = v0.z; vred[2048 + (8 * w + 3) * 64 + l] = v0.w;
            vred[2048 + (8 * w + 4) * 64 + l] = v1.x; vred[2048 + (8 * w + 5) * 64 + l] = v1.y;
            vred[2048 + (8 * w + 6) * 64 + l] = v1.z; vred[2048 + (8 * w + 7) * 64 + l] = v1.w;
        }
        __syncthreads();   // bar2: partials for both groups ready

        // ---- fixed-order all-reduce + Euler, A then B ----
        f32x4 b3lo = up4(b3p[0], b3p[1]), b3hi = up4(b3p[2], b3p[3]);
        {
            f32x4 sv0 = {0.f, 0.f, 0.f, 0.f}, sv1 = sv0;
#pragma unroll
            for (int w2 = 0; w2 < 4; w2++) {
                sv0.x += vred[(8 * w2 + 0) * 64 + l]; sv0.y += vred[(8 * w2 + 1) * 64 + l];
                sv0.z += vred[(8 * w2 + 2) * 64 + l]; sv0.w += vred[(8 * w2 + 3) * 64 + l];
                sv1.x += vred[(8 * w2 + 4) * 64 + l]; sv1.y += vred[(8 * w2 + 5) * 64 + l];
                sv1.z += vred[(8 * w2 + 6) * 64 + l]; sv1.w += vred[(8 * w2 + 7) * 64 + l];
            }
            zsA0.x -= dt * (sv0.x + b3lo.x); zsA0.y -= dt * (sv0.y + b3lo.y);
            zsA0.z -= dt * (sv0.z + b3lo.z); zsA0.w -= dt * (sv0.w + b3lo.w);
            zsA1.x -= dt * (sv1.x + b3hi.x); zsA1.y -= dt * (sv1.y + b3hi.y);
            zsA1.z -= dt * (sv1.z + b3hi.z); zsA1.w -= dt * (sv1.w + b3hi.w);
        }
        {
            f32x4 sv0 = {0.f, 0.f, 0.f, 0.f}, sv1 = sv0;
#pragma unroll
            for (int w2 = 0; w2 < 4; w2++) {
                sv0.x += vred[2048 + (8 * w2 + 0) * 64 + l]; sv0.y += vred[2048 + (8 * w2 + 1) * 64 + l];
                sv0.z += vred[2048 + (8 * w2 + 2) * 64 + l]; sv0.w += vred[2048 + (8 * w2 + 3) * 64 + l];
                sv1.x += vred[2048 + (8 * w2 + 4) * 64 + l]; sv1.y += vred[2048 + (8 * w2 + 5) * 64 + l];
                sv1.z += vred[2048 + (8 * w2 + 6) * 64 + l]; sv1.w += vred[2048 + (8 * w2 + 7) * 64 + l];
            }
            zsB0.x -= dt * (sv0.x + b3lo.x); zsB0.y -= dt * (sv0.y + b3lo.y);
            zsB0.z -= dt * (sv0.z + b3lo.z); zsB0.w -= dt * (sv0.w + b3lo.w);
            zsB1.x -= dt * (sv1.x + b3hi.x); zsB1.y -= dt * (sv1.y + b3hi.y);
            zsB1.z -= dt * (sv1.z + b3hi.z); zsB1.w -= dt * (sv1.w + b3hi.w);
        }
        // no bar: next exA writes only after bar2; vred rewritten only after bar1.
    }

    // ---- store: wave 0 -> group A, wave 1 -> group B ----
    if (w == 0) {
        float loc = locS[p];
        float* op = out + bA * (NS * NPRED) + sA * NPRED;
        f32x4 o0 = zsA0 * loc;
        *(f32x4*)(op + 4 * q) = o0;
        if (q < 2) { f32x4 o1 = zsA1 * loc; *(f32x4*)(op + 16 + 4 * q) = o1; }
    } else if (w == 1) {
        float loc = locS[16 + p];
        float* op = out + bB * (NS * NPRED) + sB * NPRED;
        f32x4 o0 = zsB0 * loc;
        *(f32x4*)(op + 4 * q) = o0;
        if (q < 2) { f32x4 o1 = zsB1 * loc; *(f32x4*)(op + 16 + 4 * q) = o1; }
    }
}

extern "C" void kernel_launch(void* const* d_in, const int* in_sizes, int n_in,
                              void* d_out, int out_size, void* d_ws, size_t ws_size,
                              hipStream_t stream) {
    const float* past_target = (const float*)d_in[0];
    // d_in[1] past_observed_values: not used by the reference math
    const float* z0 = (const float*)d_in[2];
    const float* W1 = (const float*)d_in[3];
    const float* b1 = (const float*)d_in[4];
    const float* W2 = (const float*)d_in[5];
    const float* b2 = (const float*)d_in[6];
    const float* W3 = (const float*)d_in[7];
    const float* b3 = (const float*)d_in[8];

    unsigned short* wsf = (unsigned short*)d_ws;   // 160 KB frag image (proven)

    prep_kernel<<<320, 256, 0, stream>>>(W1, W2, W3, wsf);
    fm_kernel<<<400, 256, 0, stream>>>(past_target, z0, W1, b1, b2, b3,
                                       wsf, (float*)d_out);
}

// Round 12
// 126.855 us; speedup vs baseline: 1.7746x; 1.7746x over previous
//
#include <hip/hip_runtime.h>

#define NB 128
#define NS 100
#define NPRED 24
#define NHID 256
#define NSTEPS 16
#define NCTX 96
// R9 structure (135us proven): 800 blocks x 256 thr (4 waves = 1 group of 16
// rows). Wave w owns hidden ch [64w,64w+64); W1/W2/W3 slices in registers.
// Layer 3 split by k-chunk + f32 LDS all-reduce. 2 barriers/step.
// R12 = R9 + cvtpk ONLY on VALU-produced inputs (R10-validated positions);
// cvtpk must NEVER directly read a raw MFMA accumulator (R11 NaN lesson).

typedef float f32x4 __attribute__((ext_vector_type(4)));
typedef short bf16x8 __attribute__((ext_vector_type(8)));

__device__ __forceinline__ unsigned short f2bf(float f) {
    union { float f; unsigned u; } v; v.f = f;
    return (unsigned short)((v.u + 0x7fffu + ((v.u >> 16) & 1u)) >> 16);
}
__device__ __forceinline__ unsigned pk2(float lo, float hi) {
    return (unsigned)f2bf(lo) | ((unsigned)f2bf(hi) << 16);
}
// 1-op RNE bf16 pack. ONLY use on VALU-produced values (never raw MFMA dst).
__device__ __forceinline__ unsigned cvtpk(float lo, float hi) {
    unsigned r;
    asm("v_cvt_pk_bf16_f32 %0, %1, %2" : "=v"(r) : "v"(lo), "v"(hi));
    return r;
}
__device__ __forceinline__ bf16x8 mk8(unsigned a, unsigned b, unsigned c, unsigned d) {
    union { unsigned u[4]; bf16x8 v; } x;
    x.u[0] = a; x.u[1] = b; x.u[2] = c; x.u[3] = d;
    return x.v;
}
__device__ __forceinline__ f32x4 bf4_to_f32x4(const unsigned short* pA) {
    uint2 uu = *(const uint2*)pA;
    union { unsigned u; float f; } c0, c1, c2, c3;
    c0.u = uu.x << 16; c1.u = uu.x & 0xffff0000u;
    c2.u = uu.y << 16; c3.u = uu.y & 0xffff0000u;
    f32x4 r; r.x = c0.f; r.y = c1.f; r.z = c2.f; r.w = c3.f;
    return r;
}
__device__ __forceinline__ f32x4 relu4(f32x4 a) {
    a.x = fmaxf(a.x, 0.f); a.y = fmaxf(a.y, 0.f);
    a.z = fmaxf(a.z, 0.f); a.w = fmaxf(a.w, 0.f);
    return a;
}

// k-slot permutation within a 32-wide k-block at (lane l, elem e):
//   k_local = 16*(e>>2) + 4*(l>>4) + (e&3)
// Applied identically to A and B fragments (numerically verified R2-R10).

// prep -> d_ws (ushorts): W1F [0,8192) | W3F [8192,16384) | W2F [16384,81920)
__global__ void prep_kernel(const float* __restrict__ W1,
                            const float* __restrict__ W2,
                            const float* __restrict__ W3,
                            unsigned short* __restrict__ wsf) {
    int i = blockIdx.x * 256 + threadIdx.x;   // 0..81919
    if (i < 8192) {
        int T = i >> 9, ll = (i >> 3) & 63, e = i & 7;
        int k = 16 * (e >> 2) + 4 * (ll >> 4) + (e & 3);
        int m = 16 * T + (ll & 15);
        wsf[i] = (k <= 24) ? f2bf(W1[k * NHID + m]) : (unsigned short)0;
    } else if (i < 16384) {
        int idx = i - 8192;
        int ks = idx >> 10, T = (idx >> 9) & 1, ll = (idx >> 3) & 63, e = idx & 7;
        int k = 32 * ks + 16 * (e >> 2) + 4 * (ll >> 4) + (e & 3);
        int m = 16 * T + (ll & 15);
        wsf[i] = (m < NPRED) ? f2bf(W3[k * NPRED + m]) : (unsigned short)0;
    } else {
        int idx = i - 16384;
        int ks = idx >> 13, T = (idx >> 9) & 15, ll = (idx >> 3) & 63, e = idx & 7;
        int k = 32 * ks + 16 * (e >> 2) + 4 * (ll >> 4) + (e & 3);
        int m = 16 * T + (ll & 15);
        wsf[i] = f2bf(W2[k * NHID + m]);
    }
}

__global__ __launch_bounds__(256, 2) void fm_kernel(
    const float* __restrict__ past_target,
    const float* __restrict__ z0g,
    const float* __restrict__ W1, const float* __restrict__ b1,
    const float* __restrict__ b2, const float* __restrict__ b3,
    const unsigned short* __restrict__ wsf,
    float* __restrict__ out) {
    __shared__ __attribute__((aligned(16))) unsigned short cbF[4096]; // 8 KB
    __shared__ __attribute__((aligned(16))) unsigned exA[2048];       // 8 KB h1
    __shared__ __attribute__((aligned(16))) float vredB[2048];        // 8 KB v

    const int tid = threadIdx.x;
    const int g = blockIdx.x;        // row-group 0..799

    // ---- one-time: fp32 cbias -> bf16 C-frags (16 rows x 16 ch-chunks) ----
    {
        const int r = tid >> 4, c = tid & 15;
        const int bb = (g * 16 + r) & 127;
        const float* ctxp = past_target + bb * NCTX;
        float asum = 0.f;
        for (int k = 0; k < NCTX; k++) asum += fabsf(ctxp[k]);
        float inv = 1.f / fmaxf(asum * (1.f / (float)NCTX), 1e-6f);
        f32x4 acc[4];
        const float* b1p = b1 + 16 * c;
#pragma unroll
        for (int u = 0; u < 4; u++) acc[u] = *(const f32x4*)(b1p + 4 * u);
        for (int k = 0; k < NCTX; k++) {
            float sx = ctxp[k] * inv;
            const f32x4* wr = (const f32x4*)(W1 + (26 + k) * NHID + 16 * c);
#pragma unroll
            for (int u = 0; u < 4; u++) {
                f32x4 w = wr[u];
                acc[u].x += sx * w.x; acc[u].y += sx * w.y;
                acc[u].z += sx * w.z; acc[u].w += sx * w.w;
            }
        }
        // C-frag layout: ch 16T+4qq+ii -> cbF[T*256 + qq*64 + r*4 + ii]
#pragma unroll
        for (int qq = 0; qq < 4; qq++) {
            int base = c * 256 + qq * 64 + r * 4;
            cbF[base + 0] = f2bf(acc[qq].x);
            cbF[base + 1] = f2bf(acc[qq].y);
            cbF[base + 2] = f2bf(acc[qq].z);
            cbF[base + 3] = f2bf(acc[qq].w);
        }
    }

    const int w = tid >> 6;          // wave 0..3: owns hidden ch [64w,64w+64)
    const int l = tid & 63;
    const int q = l >> 4, p = l & 15;
    const int R = g * 16 + p;
    const int s = R >> 7, b = R & 127;
    const int l8 = l * 8;

    // ---- persistent registers ----
    bf16x8 w1r[4];                   // W1 A-frags (own 4 T-chunks): 16 regs
    bf16x8 w2r[32];                  // W2 A-frags (own 64 ch x K=256): 128 regs
    bf16x8 w3r[4];                   // W3 A-frags own ks=2w,2w+1: 16 regs
#pragma unroll
    for (int j = 0; j < 4; j++)
        w1r[j] = *(const bf16x8*)(wsf + (4 * w + j) * 512 + l8);
#pragma unroll
    for (int ks = 0; ks < 8; ks++)
#pragma unroll
        for (int j = 0; j < 4; j++)
            w2r[ks * 4 + j] = *(const bf16x8*)(wsf + 16384 + (ks * 16 + 4 * w + j) * 512 + l8);
#pragma unroll
    for (int d = 0; d < 2; d++)
#pragma unroll
        for (int tt = 0; tt < 2; tt++)
            w3r[2 * d + tt] = *(const bf16x8*)(wsf + 8192 + (2 * w + d) * 1024 + tt * 512 + l8);

    f32x4 b2f[4];
#pragma unroll
    for (int j = 0; j < 4; j++)
        b2f[j] = *(const f32x4*)(b2 + (4 * w + j) * 16 + 4 * q);
    f32x4 b3f0 = *(const f32x4*)(b3 + 4 * q);
    f32x4 b3f1 = {0.f, 0.f, 0.f, 0.f};
    if (q < 2) b3f1 = *(const f32x4*)(b3 + 16 + 4 * q);

    // ---- z state (replicated across the 4 waves; fixed-order math) ----
    f32x4 zs0, zs1;
    {
        const f32x4* zr = (const f32x4*)(z0g + R * NPRED);
        zs0 = zr[q];
        f32x4 zz = {0.f, 0.f, 0.f, 0.f};
        zs1 = zz;
        if (q < 2) zs1 = zr[4 + q];
    }

    __syncthreads();   // cbF ready

    f32x4 cbr[4];
#pragma unroll
    for (int j = 0; j < 4; j++)
        cbr[j] = bf4_to_f32x4(cbF + (4 * w + j) * 256 + q * 64 + p * 4);

    const float dt = 1.f / (float)NSTEPS;
#pragma unroll 1
    for (int step = 0; step < NSTEPS; step++) {
        float t = 1.f - (float)step * dt;
        float z10 = (q == 2) ? t : zs1.x;   // channel 24 carries t
        // zs/z10 are VALU-produced -> cvtpk safe
        bf16x8 bz = mk8(cvtpk(zs0.x, zs0.y), cvtpk(zs0.z, zs0.w),
                        cvtpk(z10, zs1.y), cvtpk(zs1.z, zs1.w));

        // ---- layer 1 (own 64 ch): 4 MFMA, all-register -> exA ----
        // exA safe: step s-1's exA readers finished before bar2(s-1).
#pragma unroll
        for (int j = 0; j < 4; j++) {
            f32x4 h = relu4(__builtin_amdgcn_mfma_f32_16x16x32_bf16(w1r[j], bz, cbr[j], 0, 0, 0));
            // h is relu4 (VALU) output -> cvtpk safe
            exA[(8 * w + 2 * j) * 64 + l]     = cvtpk(h.x, h.y);
            exA[(8 * w + 2 * j + 1) * 64 + l] = cvtpk(h.z, h.w);
        }
        __syncthreads();   // bar1: h1 exchange complete

        // ---- layer 2 (own 64 ch, K=256): 32 MFMA, weights in regs ----
        f32x4 a0 = {0.f, 0.f, 0.f, 0.f}, a1 = a0, a2 = a0, a3 = a0;
#pragma unroll
        for (int ks = 0; ks < 8; ks++) {
            bf16x8 bb = mk8(exA[(4 * ks) * 64 + l], exA[(4 * ks + 1) * 64 + l],
                            exA[(4 * ks + 2) * 64 + l], exA[(4 * ks + 3) * 64 + l]);
            a0 = __builtin_amdgcn_mfma_f32_16x16x32_bf16(w2r[ks * 4 + 0], bb, a0, 0, 0, 0);
            a1 = __builtin_amdgcn_mfma_f32_16x16x32_bf16(w2r[ks * 4 + 1], bb, a1, 0, 0, 0);
            a2 = __builtin_amdgcn_mfma_f32_16x16x32_bf16(w2r[ks * 4 + 2], bb, a2, 0, 0, 0);
            a3 = __builtin_amdgcn_mfma_f32_16x16x32_bf16(w2r[ks * 4 + 3], bb, a3, 0, 0, 0);
        }
        // bias + relu + pack own h2 (VALU outputs -> cvtpk safe)
        unsigned bh2[8];
        {
            f32x4 h0 = relu4(a0 + b2f[0]), h1 = relu4(a1 + b2f[1]);
            f32x4 h2 = relu4(a2 + b2f[2]), h3 = relu4(a3 + b2f[3]);
            bh2[0] = cvtpk(h0.x, h0.y); bh2[1] = cvtpk(h0.z, h0.w);
            bh2[2] = cvtpk(h1.x, h1.y); bh2[3] = cvtpk(h1.z, h1.w);
            bh2[4] = cvtpk(h2.x, h2.y); bh2[5] = cvtpk(h2.z, h2.w);
            bh2[6] = cvtpk(h3.x, h3.y); bh2[7] = cvtpk(h3.z, h3.w);
        }

        // ---- layer 3 partial (own k-chunks ks=2w,2w+1): 4 MFMA ----
        f32x4 v0 = {0.f, 0.f, 0.f, 0.f}, v1 = v0;
        {
            bf16x8 bbA = mk8(bh2[0], bh2[1], bh2[2], bh2[3]);
            bf16x8 bbB = mk8(bh2[4], bh2[5], bh2[6], bh2[7]);
            v0 = __builtin_amdgcn_mfma_f32_16x16x32_bf16(w3r[0], bbA, v0, 0, 0, 0);
            v1 = __builtin_amdgcn_mfma_f32_16x16x32_bf16(w3r[1], bbA, v1, 0, 0, 0);
            v0 = __builtin_amdgcn_mfma_f32_16x16x32_bf16(w3r[2], bbB, v0, 0, 0, 0);
            v1 = __builtin_amdgcn_mfma_f32_16x16x32_bf16(w3r[3], bbB, v1, 0, 0, 0);
        }
        // f32 partial-v exchange (plain ds_write of MFMA dst: hazard-safe,
        // R9-proven). vredB safe: step s-1's readers finished before bar1(s).
        vredB[(8 * w + 0) * 64 + l] = v0.x;
        vredB[(8 * w + 1) * 64 + l] = v0.y;
        vredB[(8 * w + 2) * 64 + l] = v0.z;
        vredB[(8 * w + 3) * 64 + l] = v0.w;
        vredB[(8 * w + 4) * 64 + l] = v1.x;
        vredB[(8 * w + 5) * 64 + l] = v1.y;
        vredB[(8 * w + 6) * 64 + l] = v1.z;
        vredB[(8 * w + 7) * 64 + l] = v1.w;
        __syncthreads();   // bar2: partials ready

        // ---- all-reduce in FIXED order (z identical across waves) ----
        f32x4 sv0 = {0.f, 0.f, 0.f, 0.f}, sv1 = sv0;
#pragma unroll
        for (int w2 = 0; w2 < 4; w2++) {
            sv0.x += vredB[(8 * w2 + 0) * 64 + l];
            sv0.y += vredB[(8 * w2 + 1) * 64 + l];
            sv0.z += vredB[(8 * w2 + 2) * 64 + l];
            sv0.w += vredB[(8 * w2 + 3) * 64 + l];
            sv1.x += vredB[(8 * w2 + 4) * 64 + l];
            sv1.y += vredB[(8 * w2 + 5) * 64 + l];
            sv1.z += vredB[(8 * w2 + 6) * 64 + l];
            sv1.w += vredB[(8 * w2 + 7) * 64 + l];
        }

        // ---- Euler: z -= dt*(v + b3) (pad channels: v==0, b3f==0) ----
        zs0.x -= dt * (sv0.x + b3f0.x); zs0.y -= dt * (sv0.y + b3f0.y);
        zs0.z -= dt * (sv0.z + b3f0.z); zs0.w -= dt * (sv0.w + b3f0.w);
        zs1.x -= dt * (sv1.x + b3f1.x); zs1.y -= dt * (sv1.y + b3f1.y);
        zs1.z -= dt * (sv1.z + b3f1.z); zs1.w -= dt * (sv1.w + b3f1.w);
        // no bar here: next step's exA writes are safe (readers done pre-bar2),
        // next vredB writes are fenced by bar1 of the next step.
    }

    // ---- store (wave 0 only; loc recomputed once) ----
    if (w == 0) {
        const float* ctxl = past_target + b * NCTX;
        float asum = 0.f;
        for (int k = 0; k < NCTX; k++) asum += fabsf(ctxl[k]);
        float loc = fmaxf(asum * (1.f / (float)NCTX), 1e-6f);
        float* op = out + b * (NS * NPRED) + s * NPRED;
        f32x4 o0 = zs0 * loc;
        *(f32x4*)(op + 4 * q) = o0;
        if (q < 2) { f32x4 o1 = zs1 * loc; *(f32x4*)(op + 16 + 4 * q) = o1; }
    }
}

extern "C" void kernel_launch(void* const* d_in, const int* in_sizes, int n_in,
                              void* d_out, int out_size, void* d_ws, size_t ws_size,
                              hipStream_t stream) {
    const float* past_target = (const float*)d_in[0];
    // d_in[1] past_observed_values: not used by the reference math
    const float* z0 = (const float*)d_in[2];
    const float* W1 = (const float*)d_in[3];
    const float* b1 = (const float*)d_in[4];
    const float* W2 = (const float*)d_in[5];
    const float* b2 = (const float*)d_in[6];
    const float* W3 = (const float*)d_in[7];
    const float* b3 = (const float*)d_in[8];

    unsigned short* wsf = (unsigned short*)d_ws;   // 160 KB frag image (proven)

    prep_kernel<<<320, 256, 0, stream>>>(W1, W2, W3, wsf);
    fm_kernel<<<800, 256, 0, stream>>>(past_target, z0, W1, b1, b2, b3,
                                       wsf, (float*)d_out);
}